// Round 1
// baseline (975.001 us; speedup 1.0000x reference)
//
#include <hip/hip_runtime.h>
#include <math.h>

#define HW32 1024
#define HW64 4096
#define KCAM 21
#define TP 64

// ---------------------------------------------------------------------------
// Kernel A: 1x1 convs at 32x32: a32[n][j][p] = sum_c w_aspp[j][c]*aspp[n][c][p]
//           g32 likewise from f3/w_f3. grid (4 ptiles, 2 which, 8 n), 256 thr.
// ---------------------------------------------------------------------------
__global__ __launch_bounds__(256) void k_conv32(
    const float* __restrict__ aspp, const float* __restrict__ f3,
    const float* __restrict__ w_aspp, const float* __restrict__ w_f3,
    float* __restrict__ a32, float* __restrict__ g32)
{
  const int pt = blockIdx.x, which = blockIdx.y, n = blockIdx.z;
  const float* x = (which == 0 ? aspp : f3) + (size_t)n * 128 * HW32;
  const float* w = (which == 0 ? w_aspp : w_f3);
  float* out = (which == 0 ? a32 : g32) + (size_t)n * 64 * HW32;

  __shared__ __align__(16) float wlds[64 * 128];
  for (int i = threadIdx.x; i < 64 * 128; i += 256) wlds[i] = w[i];
  __syncthreads();

  const int p = pt * 256 + threadIdx.x;
  float acc[64];
#pragma unroll
  for (int j = 0; j < 64; ++j) acc[j] = 0.f;

  for (int c0 = 0; c0 < 128; c0 += 8) {
    float xv[8];
#pragma unroll
    for (int cc = 0; cc < 8; ++cc) xv[cc] = x[(size_t)(c0 + cc) * HW32 + p];
#pragma unroll
    for (int j = 0; j < 64; ++j) {
      const float4 w0 = *reinterpret_cast<const float4*>(&wlds[j * 128 + c0]);
      const float4 w1 = *reinterpret_cast<const float4*>(&wlds[j * 128 + c0 + 4]);
      acc[j] = fmaf(w0.x, xv[0], acc[j]);
      acc[j] = fmaf(w0.y, xv[1], acc[j]);
      acc[j] = fmaf(w0.z, xv[2], acc[j]);
      acc[j] = fmaf(w0.w, xv[3], acc[j]);
      acc[j] = fmaf(w1.x, xv[4], acc[j]);
      acc[j] = fmaf(w1.y, xv[5], acc[j]);
      acc[j] = fmaf(w1.z, xv[6], acc[j]);
      acc[j] = fmaf(w1.w, xv[7], acc[j]);
    }
  }
  for (int j = 0; j < 64; ++j) out[(size_t)j * HW32 + p] = acc[j];
}

// ---------------------------------------------------------------------------
// Kernel B: build normalized f[n][pos][128].
// Per block: one (n, y) output row (64 x positions).
// Phase 1: bilinear-sample 132 feature channels into LDS feat[132][64].
//   feat 0..3   : inp (512x512, scale 511/63)
//   feat 4..67  : a32 (32x32, scale 31/63)
//   feat 68..131: g32 (32x32, scale 31/63)
// Phase 2: f_pre[o] = sum_c w_f9[o][c]*feat[c][x]; normalize over o; store.
// grid (64 y, 8 n), 256 threads.
// ---------------------------------------------------------------------------
__global__ __launch_bounds__(256) void k_build_f(
    const float* __restrict__ inp, const float* __restrict__ a32,
    const float* __restrict__ g32, const float* __restrict__ w_f9,
    float* __restrict__ fbuf)
{
  const int y = blockIdx.x, n = blockIdx.y;

  __shared__ __align__(16) float wlds[128 * 132];
  __shared__ float feat[132 * 64];
  __shared__ float nrm[4][64];

  for (int i = threadIdx.x; i < 128 * 132; i += 256) wlds[i] = w_f9[i];

  const float s512 = 511.f / 63.f, s32 = 31.f / 63.f;
  const float syA = y * s512;
  const int y0A = (int)syA;
  const float wyA = syA - (float)y0A;
  const int y1A = min(y0A + 1, 511);
  const float syB = y * s32;
  const int y0B = (int)syB;
  const float wyB = syB - (float)y0B;
  const int y1B = min(y0B + 1, 31);

  for (int idx = threadIdx.x; idx < 132 * 64; idx += 256) {
    const int c = idx >> 6, x = idx & 63;
    float v;
    if (c < 4) {
      const float sx = x * s512;
      const int x0 = (int)sx;
      const float wx = sx - (float)x0;
      const int x1 = min(x0 + 1, 511);
      const float* im = inp + (size_t)(n * 4 + c) * 512 * 512;
      const float v00 = im[y0A * 512 + x0], v01 = im[y0A * 512 + x1];
      const float v10 = im[y1A * 512 + x0], v11 = im[y1A * 512 + x1];
      v = (v00 * (1.f - wx) + v01 * wx) * (1.f - wyA) +
          (v10 * (1.f - wx) + v11 * wx) * wyA;
    } else {
      const float* im = (c < 68) ? a32 + (size_t)(n * 64 + (c - 4)) * HW32
                                 : g32 + (size_t)(n * 64 + (c - 68)) * HW32;
      const float sx = x * s32;
      const int x0 = (int)sx;
      const float wx = sx - (float)x0;
      const int x1 = min(x0 + 1, 31);
      const float v00 = im[y0B * 32 + x0], v01 = im[y0B * 32 + x1];
      const float v10 = im[y1B * 32 + x0], v11 = im[y1B * 32 + x1];
      v = (v00 * (1.f - wx) + v01 * wx) * (1.f - wyB) +
          (v10 * (1.f - wx) + v11 * wx) * wyB;
    }
    feat[c * 64 + x] = v;
  }
  __syncthreads();

  const int x = threadIdx.x & 63;
  const int og = (threadIdx.x >> 6) * 32;

  float acc[32];
#pragma unroll
  for (int i = 0; i < 32; ++i) acc[i] = 0.f;

  for (int c0 = 0; c0 < 132; c0 += 4) {
    const float f0 = feat[(c0 + 0) * 64 + x];
    const float f1 = feat[(c0 + 1) * 64 + x];
    const float f2 = feat[(c0 + 2) * 64 + x];
    const float f3v = feat[(c0 + 3) * 64 + x];
#pragma unroll
    for (int i = 0; i < 32; ++i) {
      const float4 wv = *reinterpret_cast<const float4*>(&wlds[(og + i) * 132 + c0]);
      acc[i] = fmaf(wv.x, f0, acc[i]);
      acc[i] = fmaf(wv.y, f1, acc[i]);
      acc[i] = fmaf(wv.z, f2, acc[i]);
      acc[i] = fmaf(wv.w, f3v, acc[i]);
    }
  }

  float ss = 0.f;
#pragma unroll
  for (int i = 0; i < 32; ++i) ss = fmaf(acc[i], acc[i], ss);
  nrm[threadIdx.x >> 6][x] = ss;
  __syncthreads();
  const float tot = nrm[0][x] + nrm[1][x] + nrm[2][x] + nrm[3][x];
  const float inv = 1.f / (sqrtf(tot) + 1e-5f);

  float* fo = fbuf + ((size_t)n * HW64 + (size_t)y * 64 + x) * 128 + og;
#pragma unroll
  for (int i = 0; i < 32; ++i) fo[i] = acc[i] * inv;
}

// ---------------------------------------------------------------------------
// Kernel C: fused affinity + cam. Each thread owns one q column (f_q in VGPRs),
// loops over a 1024-wide p range in tiles of TP=64 staged in LDS.
// num[k][q] = sum_p cam[k][p]*relu(f_p . f_q); den[q] = sum_p relu(.).
// grid (16 qtiles, 4 psplits, 8 n), 256 threads.
// part layout: [n][ps][22][4096]  (22nd row = den)
// ---------------------------------------------------------------------------
__global__ __launch_bounds__(256) void k_affcam(
    const float* __restrict__ fbuf, const float* __restrict__ cam,
    float* __restrict__ part)
{
  const int qt = blockIdx.x, ps = blockIdx.y, n = blockIdx.z;
  const int q = qt * 256 + threadIdx.x;

  __shared__ __align__(16) float fp_lds[TP * 128];
  __shared__ float cam_lds[KCAM * TP];

  float fq[128];
  {
    const float4* fq4 =
        reinterpret_cast<const float4*>(fbuf + ((size_t)n * HW64 + q) * 128);
#pragma unroll
    for (int i = 0; i < 32; ++i) {
      const float4 v = fq4[i];
      fq[4 * i + 0] = v.x;
      fq[4 * i + 1] = v.y;
      fq[4 * i + 2] = v.z;
      fq[4 * i + 3] = v.w;
    }
  }

  float num[KCAM];
#pragma unroll
  for (int k = 0; k < KCAM; ++k) num[k] = 0.f;
  float den = 0.f;

  const int pbeg = ps * 1024;
  for (int p0 = pbeg; p0 < pbeg + 1024; p0 += TP) {
    __syncthreads();
    {
      const float4* src =
          reinterpret_cast<const float4*>(fbuf + ((size_t)n * HW64 + p0) * 128);
      float4* dst = reinterpret_cast<float4*>(fp_lds);
#pragma unroll
      for (int i = 0; i < 8; ++i)
        dst[threadIdx.x + 256 * i] = src[threadIdx.x + 256 * i];
      for (int i = threadIdx.x; i < KCAM * TP; i += 256) {
        const int k = i >> 6, col = i & 63;
        cam_lds[i] = cam[((size_t)n * KCAM + k) * HW64 + p0 + col];
      }
    }
    __syncthreads();

    for (int p = 0; p < TP; ++p) {
      const float4* fp4 = reinterpret_cast<const float4*>(&fp_lds[p * 128]);
      float d0 = 0.f, d1 = 0.f, d2 = 0.f, d3 = 0.f;
#pragma unroll
      for (int i = 0; i < 32; ++i) {
        const float4 a = fp4[i];
        d0 = fmaf(a.x, fq[4 * i + 0], d0);
        d1 = fmaf(a.y, fq[4 * i + 1], d1);
        d2 = fmaf(a.z, fq[4 * i + 2], d2);
        d3 = fmaf(a.w, fq[4 * i + 3], d3);
      }
      float s = (d0 + d1) + (d2 + d3);
      s = fmaxf(s, 0.f);
      den += s;
#pragma unroll
      for (int k = 0; k < KCAM; ++k)
        num[k] = fmaf(cam_lds[k * TP + p], s, num[k]);
    }
  }

  float* po = part + ((size_t)(n * 4 + ps) * 22) * HW64 + q;
#pragma unroll
  for (int k = 0; k < KCAM; ++k) po[(size_t)k * HW64] = num[k];
  po[(size_t)21 * HW64] = den;
}

// ---------------------------------------------------------------------------
// Kernel D: combine 4 p-split partials, divide.
// out[n][k][q] = num/(den+1e-5)
// ---------------------------------------------------------------------------
__global__ __launch_bounds__(256) void k_final(
    const float* __restrict__ part, float* __restrict__ out, int total)
{
  const int idx = blockIdx.x * 256 + threadIdx.x;
  if (idx >= total) return;
  const int n = idx / (KCAM * HW64);
  const int r = idx - n * (KCAM * HW64);
  const int k = r >> 12;
  const int q = r & 4095;
  const float* base = part + (size_t)n * 4 * 22 * HW64;
  float num = 0.f, den = 0.f;
#pragma unroll
  for (int ps = 0; ps < 4; ++ps) {
    num += base[((size_t)ps * 22 + k) * HW64 + q];
    den += base[((size_t)ps * 22 + 21) * HW64 + q];
  }
  out[idx] = num / (den + 1e-5f);
}

// ---------------------------------------------------------------------------
extern "C" void kernel_launch(void* const* d_in, const int* in_sizes, int n_in,
                              void* d_out, int out_size, void* d_ws, size_t ws_size,
                              hipStream_t stream) {
  const float* aspp   = (const float*)d_in[0];  // [8,128,32,32]
  const float* f3     = (const float*)d_in[1];  // [8,128,32,32]
  const float* inp    = (const float*)d_in[2];  // [8,4,512,512]
  const float* cam    = (const float*)d_in[3];  // [8,21,64,64]
  const float* w_aspp = (const float*)d_in[4];  // [64,128]
  const float* w_f3   = (const float*)d_in[5];  // [64,128]
  const float* w_f9   = (const float*)d_in[6];  // [128,132]
  float* out = (float*)d_out;

  float* ws   = (float*)d_ws;
  float* a32  = ws;                      // 8*64*1024      = 524288
  float* g32  = a32 + 524288;            // 524288
  float* fbuf = g32 + 524288;            // 8*4096*128     = 4194304
  float* part = fbuf + 4194304;          // 8*4*22*4096    = 2883584

  k_conv32<<<dim3(4, 2, 8), 256, 0, stream>>>(aspp, f3, w_aspp, w_f3, a32, g32);
  k_build_f<<<dim3(64, 8), 256, 0, stream>>>(inp, a32, g32, w_f9, fbuf);
  k_affcam<<<dim3(16, 4, 8), 256, 0, stream>>>(fbuf, cam, part);
  k_final<<<2688, 256, 0, stream>>>(part, out, 8 * KCAM * HW64);
}

// Round 2
// 263.719 us; speedup vs baseline: 3.6971x; 3.6971x over previous
//
#include <hip/hip_runtime.h>
#include <math.h>

typedef unsigned short u16;
typedef unsigned int u32;
typedef __attribute__((ext_vector_type(8))) short bf16x8;
typedef __attribute__((ext_vector_type(4))) short short4v;
typedef __attribute__((ext_vector_type(4))) float f32x4;

#define HW32 1024
#define HW64 4096
#define KCAM 21
#define QB 256
#define PB 64
#define PSPLIT 2
#define FH_STR 136   // u16 stride for f LDS rows (128 + 8 pad)
#define WB_STR 72    // u16 stride for w LDS rows (64 + 8 pad)
#define CA_STR 72    // u16 stride for cam LDS rows

static __device__ __forceinline__ u16 f2bf(float x) {
  u32 u = __float_as_uint(x);
  u32 r = (u + 0x7FFFu + ((u >> 16) & 1u)) >> 16;
  return (u16)r;
}
static __device__ __forceinline__ float bf2f(u16 h) {
  return __uint_as_float(((u32)h) << 16);
}

// ---------------------------------------------------------------------------
// Kernel A: 1x1 convs at 32x32 (f32, unchanged).
// ---------------------------------------------------------------------------
__global__ __launch_bounds__(256) void k_conv32(
    const float* __restrict__ aspp, const float* __restrict__ f3,
    const float* __restrict__ w_aspp, const float* __restrict__ w_f3,
    float* __restrict__ a32, float* __restrict__ g32)
{
  const int pt = blockIdx.x, which = blockIdx.y, n = blockIdx.z;
  const float* x = (which == 0 ? aspp : f3) + (size_t)n * 128 * HW32;
  const float* w = (which == 0 ? w_aspp : w_f3);
  float* out = (which == 0 ? a32 : g32) + (size_t)n * 64 * HW32;

  __shared__ __align__(16) float wlds[64 * 128];
  for (int i = threadIdx.x; i < 64 * 128; i += 256) wlds[i] = w[i];
  __syncthreads();

  const int p = pt * 256 + threadIdx.x;
  float acc[64];
#pragma unroll
  for (int j = 0; j < 64; ++j) acc[j] = 0.f;

  for (int c0 = 0; c0 < 128; c0 += 8) {
    float xv[8];
#pragma unroll
    for (int cc = 0; cc < 8; ++cc) xv[cc] = x[(size_t)(c0 + cc) * HW32 + p];
#pragma unroll
    for (int j = 0; j < 64; ++j) {
      const float4 w0 = *reinterpret_cast<const float4*>(&wlds[j * 128 + c0]);
      const float4 w1 = *reinterpret_cast<const float4*>(&wlds[j * 128 + c0 + 4]);
      acc[j] = fmaf(w0.x, xv[0], acc[j]);
      acc[j] = fmaf(w0.y, xv[1], acc[j]);
      acc[j] = fmaf(w0.z, xv[2], acc[j]);
      acc[j] = fmaf(w0.w, xv[3], acc[j]);
      acc[j] = fmaf(w1.x, xv[4], acc[j]);
      acc[j] = fmaf(w1.y, xv[5], acc[j]);
      acc[j] = fmaf(w1.z, xv[6], acc[j]);
      acc[j] = fmaf(w1.w, xv[7], acc[j]);
    }
  }
  for (int j = 0; j < 64; ++j) out[(size_t)j * HW32 + p] = acc[j];
}

// ---------------------------------------------------------------------------
// Kernel B: build normalized f, emitted as split bf16 (hi/lo) [n][pos][128].
// ---------------------------------------------------------------------------
__global__ __launch_bounds__(256) void k_build_f(
    const float* __restrict__ inp, const float* __restrict__ a32,
    const float* __restrict__ g32, const float* __restrict__ w_f9,
    u16* __restrict__ fhi_g, u16* __restrict__ flo_g)
{
  const int y = blockIdx.x, n = blockIdx.y;

  __shared__ __align__(16) float wlds[128 * 132];
  __shared__ float feat[132 * 64];
  __shared__ float nrm[4][64];

  for (int i = threadIdx.x; i < 128 * 132; i += 256) wlds[i] = w_f9[i];

  const float s512 = 511.f / 63.f, s32 = 31.f / 63.f;
  const float syA = y * s512;
  const int y0A = (int)syA;
  const float wyA = syA - (float)y0A;
  const int y1A = min(y0A + 1, 511);
  const float syB = y * s32;
  const int y0B = (int)syB;
  const float wyB = syB - (float)y0B;
  const int y1B = min(y0B + 1, 31);

  for (int idx = threadIdx.x; idx < 132 * 64; idx += 256) {
    const int c = idx >> 6, x = idx & 63;
    float v;
    if (c < 4) {
      const float sx = x * s512;
      const int x0 = (int)sx;
      const float wx = sx - (float)x0;
      const int x1 = min(x0 + 1, 511);
      const float* im = inp + (size_t)(n * 4 + c) * 512 * 512;
      const float v00 = im[y0A * 512 + x0], v01 = im[y0A * 512 + x1];
      const float v10 = im[y1A * 512 + x0], v11 = im[y1A * 512 + x1];
      v = (v00 * (1.f - wx) + v01 * wx) * (1.f - wyA) +
          (v10 * (1.f - wx) + v11 * wx) * wyA;
    } else {
      const float* im = (c < 68) ? a32 + (size_t)(n * 64 + (c - 4)) * HW32
                                 : g32 + (size_t)(n * 64 + (c - 68)) * HW32;
      const float sx = x * s32;
      const int x0 = (int)sx;
      const float wx = sx - (float)x0;
      const int x1 = min(x0 + 1, 31);
      const float v00 = im[y0B * 32 + x0], v01 = im[y0B * 32 + x1];
      const float v10 = im[y1B * 32 + x0], v11 = im[y1B * 32 + x1];
      v = (v00 * (1.f - wx) + v01 * wx) * (1.f - wyB) +
          (v10 * (1.f - wx) + v11 * wx) * wyB;
    }
    feat[c * 64 + x] = v;
  }
  __syncthreads();

  const int x = threadIdx.x & 63;
  const int og = (threadIdx.x >> 6) * 32;

  float acc[32];
#pragma unroll
  for (int i = 0; i < 32; ++i) acc[i] = 0.f;

  for (int c0 = 0; c0 < 132; c0 += 4) {
    const float f0 = feat[(c0 + 0) * 64 + x];
    const float f1 = feat[(c0 + 1) * 64 + x];
    const float f2 = feat[(c0 + 2) * 64 + x];
    const float f3v = feat[(c0 + 3) * 64 + x];
#pragma unroll
    for (int i = 0; i < 32; ++i) {
      const float4 wv = *reinterpret_cast<const float4*>(&wlds[(og + i) * 132 + c0]);
      acc[i] = fmaf(wv.x, f0, acc[i]);
      acc[i] = fmaf(wv.y, f1, acc[i]);
      acc[i] = fmaf(wv.z, f2, acc[i]);
      acc[i] = fmaf(wv.w, f3v, acc[i]);
    }
  }

  float ss = 0.f;
#pragma unroll
  for (int i = 0; i < 32; ++i) ss = fmaf(acc[i], acc[i], ss);
  nrm[threadIdx.x >> 6][x] = ss;
  __syncthreads();
  const float tot = nrm[0][x] + nrm[1][x] + nrm[2][x] + nrm[3][x];
  const float inv = 1.f / (sqrtf(tot) + 1e-5f);

  const size_t base = ((size_t)n * HW64 + (size_t)y * 64 + x) * 128 + og;
#pragma unroll
  for (int i = 0; i < 32; ++i) {
    const float v = acc[i] * inv;
    const u16 h = f2bf(v);
    fhi_g[base + i] = h;
    flo_g[base + i] = f2bf(v - bf2f(h));
  }
}

// ---------------------------------------------------------------------------
// Kernel C: fused affinity+cam via split-bf16 MFMA.
// Block: 512 thr = 8 waves (wp in {0,1}: p-subrows / stage-2 cam rowfrag;
//        wq in {0..3}: 64-wide q quarter). QB=256 q per block, p-range 2048.
// grid 256 = (n & 7 XCD-swizzled) x 16 q-tiles x 2 p-splits.
// Stage 1: S[64x256] = relu(F_p . F_q) via 3-pass split bf16 MFMA.
// Stage 2: num[32x256] += camA[32x64p] @ w[64p x 256q], row 21 of cam = ones
//          so den falls out as output row 21. 3-pass split bf16.
// part layout: [n][ps][22][4096]
// ---------------------------------------------------------------------------
__global__ __launch_bounds__(512, 2) void k_fused(
    const u16* __restrict__ fhi_g, const u16* __restrict__ flo_g,
    const float* __restrict__ cam, float* __restrict__ part)
{
  __shared__ __align__(16) u16 fhi_lds[PB * FH_STR];
  __shared__ __align__(16) u16 flo_lds[PB * FH_STR];
  __shared__ __align__(16) u16 wbhi[QB * WB_STR];
  __shared__ __align__(16) u16 wblo[QB * WB_STR];
  __shared__ __align__(16) u16 camhi[32 * CA_STR];
  __shared__ __align__(16) u16 camlo[32 * CA_STR];

  const int gx = blockIdx.x;
  const int n = gx & 7;            // XCD-swizzle: same n -> same XCD L2
  const int rest = gx >> 3;
  const int qt = rest & 15;
  const int ps = rest >> 4;
  const int tid = threadIdx.x;
  const int lane = tid & 63;
  const int wave = tid >> 6;
  const int wq = wave & 3;
  const int wp = wave >> 2;
  const int l15 = lane & 15;
  const int l4 = lane >> 4;
  const int qb = qt * QB;

  // ---- B preload (q-side F fragments), resident all kernel: 128 VGPRs x2
  bf16x8 Bhi[4][4], Blo[4][4];
#pragma unroll
  for (int qf = 0; qf < 4; ++qf) {
    const size_t rowo = ((size_t)n * HW64 + qb + wq * 64 + qf * 16 + l15) * 128;
#pragma unroll
    for (int s = 0; s < 4; ++s) {
      const int k = s * 32 + l4 * 8;
      Bhi[qf][s] = *(const bf16x8*)(fhi_g + rowo + k);
      Blo[qf][s] = *(const bf16x8*)(flo_g + rowo + k);
    }
  }

  f32x4 nacc[4];
#pragma unroll
  for (int qf = 0; qf < 4; ++qf) nacc[qf] = {0.f, 0.f, 0.f, 0.f};

  const int p_base = ps * (HW64 / PSPLIT);
  for (int t = 0; t < (HW64 / PSPLIT) / PB; ++t) {
    const int p0 = p_base + t * PB;

    // ---- stage F tile (64 p-rows x 128 ch, hi & lo)
    {
      const int p = tid >> 3;
      const int k = (tid & 7) * 16;
      const size_t go = ((size_t)n * HW64 + p0 + p) * 128 + k;
      *(bf16x8*)&fhi_lds[p * FH_STR + k]     = *(const bf16x8*)(fhi_g + go);
      *(bf16x8*)&fhi_lds[p * FH_STR + k + 8] = *(const bf16x8*)(fhi_g + go + 8);
      *(bf16x8*)&flo_lds[p * FH_STR + k]     = *(const bf16x8*)(flo_g + go);
      *(bf16x8*)&flo_lds[p * FH_STR + k + 8] = *(const bf16x8*)(flo_g + go + 8);
    }
    // ---- stage camA tile (rows 0..20 cam, 21 ones, 22..31 zero)
    for (int i = tid; i < 32 * 64; i += 512) {
      const int r = i >> 6, p = i & 63;
      float v = 0.f;
      if (r < KCAM) v = cam[((size_t)n * KCAM + r) * HW64 + p0 + p];
      else if (r == KCAM) v = 1.f;
      const u16 h = f2bf(v);
      camhi[r * CA_STR + p] = h;
      camlo[r * CA_STR + p] = f2bf(v - bf2f(h));
    }
    __syncthreads();

    // ---- Stage 1: S-tile MFMA (3-pass split)
    f32x4 acc[2][4];
#pragma unroll
    for (int pf = 0; pf < 2; ++pf)
#pragma unroll
      for (int qf = 0; qf < 4; ++qf) acc[pf][qf] = {0.f, 0.f, 0.f, 0.f};

#pragma unroll
    for (int s = 0; s < 4; ++s) {
      const int koff = s * 32 + l4 * 8;
      bf16x8 Ahi[2], Alo[2];
#pragma unroll
      for (int pf = 0; pf < 2; ++pf) {
        const int prow = wp * 32 + pf * 16 + l15;
        Ahi[pf] = *(const bf16x8*)&fhi_lds[prow * FH_STR + koff];
        Alo[pf] = *(const bf16x8*)&flo_lds[prow * FH_STR + koff];
      }
#pragma unroll
      for (int pf = 0; pf < 2; ++pf)
#pragma unroll
        for (int qf = 0; qf < 4; ++qf) {
          acc[pf][qf] = __builtin_amdgcn_mfma_f32_16x16x32_bf16(Ahi[pf], Bhi[qf][s], acc[pf][qf], 0, 0, 0);
          acc[pf][qf] = __builtin_amdgcn_mfma_f32_16x16x32_bf16(Ahi[pf], Blo[qf][s], acc[pf][qf], 0, 0, 0);
          acc[pf][qf] = __builtin_amdgcn_mfma_f32_16x16x32_bf16(Alo[pf], Bhi[qf][s], acc[pf][qf], 0, 0, 0);
        }
    }

    // ---- relu + split + write w to LDS in B-layout [q][p]
#pragma unroll
    for (int pf = 0; pf < 2; ++pf) {
      const int prow = wp * 32 + pf * 16 + l4 * 4;  // C-layout row base
#pragma unroll
      for (int qf = 0; qf < 4; ++qf) {
        const int q = wq * 64 + qf * 16 + l15;      // C-layout col
        short4v h4, lo4;
#pragma unroll
        for (int i = 0; i < 4; ++i) {
          float v = fmaxf(acc[pf][qf][i], 0.f);
          const u16 h = f2bf(v);
          h4[i] = (short)h;
          lo4[i] = (short)f2bf(v - bf2f(h));
        }
        *(short4v*)&wbhi[q * WB_STR + prow] = h4;
        *(short4v*)&wblo[q * WB_STR + prow] = lo4;
      }
    }
    __syncthreads();

    // ---- Stage 2: num += camA @ w (3-pass split), K = 64 p (2 ksteps)
#pragma unroll
    for (int s2 = 0; s2 < 2; ++s2) {
      const int koff = s2 * 32 + l4 * 8;
      const int crow = wp * 16 + l15;
      const bf16x8 Chi = *(const bf16x8*)&camhi[crow * CA_STR + koff];
      const bf16x8 Clo = *(const bf16x8*)&camlo[crow * CA_STR + koff];
#pragma unroll
      for (int qf = 0; qf < 4; ++qf) {
        const int q = wq * 64 + qf * 16 + l15;
        const bf16x8 Whi = *(const bf16x8*)&wbhi[q * WB_STR + koff];
        const bf16x8 Wlo = *(const bf16x8*)&wblo[q * WB_STR + koff];
        nacc[qf] = __builtin_amdgcn_mfma_f32_16x16x32_bf16(Chi, Whi, nacc[qf], 0, 0, 0);
        nacc[qf] = __builtin_amdgcn_mfma_f32_16x16x32_bf16(Chi, Wlo, nacc[qf], 0, 0, 0);
        nacc[qf] = __builtin_amdgcn_mfma_f32_16x16x32_bf16(Clo, Whi, nacc[qf], 0, 0, 0);
      }
    }
    __syncthreads();  // protect LDS for next tile's staging
  }

  // ---- epilogue: write num/den partials
#pragma unroll
  for (int qf = 0; qf < 4; ++qf) {
    const int qg = qb + wq * 64 + qf * 16 + l15;
#pragma unroll
    for (int i = 0; i < 4; ++i) {
      const int row = wp * 16 + l4 * 4 + i;
      if (row < 22)
        part[(((size_t)n * PSPLIT + ps) * 22 + row) * HW64 + qg] = nacc[qf][i];
    }
  }
}

// ---------------------------------------------------------------------------
// Kernel D: combine 2 p-split partials, divide.
// ---------------------------------------------------------------------------
__global__ __launch_bounds__(256) void k_final(
    const float* __restrict__ part, float* __restrict__ out, int total)
{
  const int idx = blockIdx.x * 256 + threadIdx.x;
  if (idx >= total) return;
  const int n = idx / (KCAM * HW64);
  const int r = idx - n * (KCAM * HW64);
  const int k = r >> 12;
  const int q = r & 4095;
  const float* base = part + (size_t)n * PSPLIT * 22 * HW64;
  float num = 0.f, den = 0.f;
#pragma unroll
  for (int p = 0; p < PSPLIT; ++p) {
    num += base[((size_t)p * 22 + k) * HW64 + q];
    den += base[((size_t)p * 22 + 21) * HW64 + q];
  }
  out[idx] = num / (den + 1e-5f);
}

// ---------------------------------------------------------------------------
extern "C" void kernel_launch(void* const* d_in, const int* in_sizes, int n_in,
                              void* d_out, int out_size, void* d_ws, size_t ws_size,
                              hipStream_t stream) {
  const float* aspp   = (const float*)d_in[0];
  const float* f3     = (const float*)d_in[1];
  const float* inp    = (const float*)d_in[2];
  const float* cam    = (const float*)d_in[3];
  const float* w_aspp = (const float*)d_in[4];
  const float* w_f3   = (const float*)d_in[5];
  const float* w_f9   = (const float*)d_in[6];
  float* out = (float*)d_out;

  float* ws   = (float*)d_ws;
  float* a32  = ws;                            // 524288 f32
  float* g32  = a32 + 524288;                  // 524288 f32
  float* part = g32 + 524288;                  // 8*2*22*4096 = 1441792 f32
  u16*   fhi  = (u16*)(part + 1441792);        // 8*4096*128 u16
  u16*   flo  = fhi + 4194304;                 // 8*4096*128 u16
  // total = 26.7 MB

  k_conv32<<<dim3(4, 2, 8), 256, 0, stream>>>(aspp, f3, w_aspp, w_f3, a32, g32);
  k_build_f<<<dim3(64, 8), 256, 0, stream>>>(inp, a32, g32, w_f9, fhi, flo);
  k_fused<<<256, 512, 0, stream>>>(fhi, flo, cam, part);
  k_final<<<2688, 256, 0, stream>>>(part, out, 8 * KCAM * HW64);
}

// Round 5
// 158.239 us; speedup vs baseline: 6.1616x; 1.6666x over previous
//
#include <hip/hip_runtime.h>
#include <math.h>

typedef unsigned short u16;
typedef unsigned int u32;
typedef __attribute__((ext_vector_type(8))) short bf16x8;
typedef __attribute__((ext_vector_type(4))) float f32x4;

#define HW32 1024
#define HW64 4096
#define KCAM 21
#define PB 32
#define PSPLIT 4
#define FH_STR 136   // u16 LDS row stride (128 + 8 pad): 272B = 17*16B -> conflict-free b128

static __device__ __forceinline__ u16 f2bf(float x) {
  u32 u = __float_as_uint(x);
  u32 r = (u + 0x7FFFu + ((u >> 16) & 1u)) >> 16;
  return (u16)r;
}

// ---------------------------------------------------------------------------
// Kernel A: 1x1 convs at 32x32 (f32). grid (4 ptiles, 2 which x 2 jhalf, 8 n).
// ---------------------------------------------------------------------------
__global__ __launch_bounds__(256) void k_conv32(
    const float* __restrict__ aspp, const float* __restrict__ f3,
    const float* __restrict__ w_aspp, const float* __restrict__ w_f3,
    float* __restrict__ a32, float* __restrict__ g32)
{
  const int pt = blockIdx.x, which = blockIdx.y >> 1, jh = blockIdx.y & 1,
            n = blockIdx.z;
  const float* x = (which == 0 ? aspp : f3) + (size_t)n * 128 * HW32;
  const float* w = (which == 0 ? w_aspp : w_f3) + jh * 32 * 128;
  float* out = (which == 0 ? a32 : g32) + (size_t)n * 64 * HW32 + (size_t)jh * 32 * HW32;

  __shared__ __align__(16) float wlds[32 * 128];
  for (int i = threadIdx.x; i < 32 * 128; i += 256) wlds[i] = w[i];
  __syncthreads();

  const int p = pt * 256 + threadIdx.x;
  float acc[32];
#pragma unroll
  for (int j = 0; j < 32; ++j) acc[j] = 0.f;

  for (int c0 = 0; c0 < 128; c0 += 8) {
    float xv[8];
#pragma unroll
    for (int cc = 0; cc < 8; ++cc) xv[cc] = x[(size_t)(c0 + cc) * HW32 + p];
#pragma unroll
    for (int j = 0; j < 32; ++j) {
      const float4 w0 = *reinterpret_cast<const float4*>(&wlds[j * 128 + c0]);
      const float4 w1 = *reinterpret_cast<const float4*>(&wlds[j * 128 + c0 + 4]);
      acc[j] = fmaf(w0.x, xv[0], acc[j]);
      acc[j] = fmaf(w0.y, xv[1], acc[j]);
      acc[j] = fmaf(w0.z, xv[2], acc[j]);
      acc[j] = fmaf(w0.w, xv[3], acc[j]);
      acc[j] = fmaf(w1.x, xv[4], acc[j]);
      acc[j] = fmaf(w1.y, xv[5], acc[j]);
      acc[j] = fmaf(w1.z, xv[6], acc[j]);
      acc[j] = fmaf(w1.w, xv[7], acc[j]);
    }
  }
  for (int j = 0; j < 32; ++j) out[(size_t)j * HW32 + p] = acc[j];
}

// ---------------------------------------------------------------------------
// Kernel A2: camA[n][32][4096] bf16: rows 0..20 = cam, row 21 = 1.0, rest 0.
// ---------------------------------------------------------------------------
__global__ __launch_bounds__(256) void k_cam(
    const float* __restrict__ cam, u16* __restrict__ camA)
{
  const int idx = blockIdx.x * 256 + threadIdx.x;   // 8*32*4096 total
  const int n = idx >> 17;
  const int r = (idx >> 12) & 31;
  const int p = idx & 4095;
  float v = 0.f;
  if (r < KCAM) v = cam[((size_t)n * KCAM + r) * HW64 + p];
  else if (r == KCAM) v = 1.f;
  camA[idx] = f2bf(v);
}

// ---------------------------------------------------------------------------
// Kernel B: build normalized f as bf16 (RN) [n][pos][128].
// ---------------------------------------------------------------------------
__global__ __launch_bounds__(256) void k_build_f(
    const float* __restrict__ inp, const float* __restrict__ a32,
    const float* __restrict__ g32, const float* __restrict__ w_f9,
    u16* __restrict__ fhi_g)
{
  const int y = blockIdx.x, n = blockIdx.y;

  __shared__ __align__(16) float wlds[128 * 132];
  __shared__ float feat[132 * 64];
  __shared__ float nrm[4][64];

  for (int i = threadIdx.x; i < 128 * 132; i += 256) wlds[i] = w_f9[i];

  const float s512 = 511.f / 63.f, s32 = 31.f / 63.f;
  const float syA = y * s512;
  const int y0A = (int)syA;
  const float wyA = syA - (float)y0A;
  const int y1A = min(y0A + 1, 511);
  const float syB = y * s32;
  const int y0B = (int)syB;
  const float wyB = syB - (float)y0B;
  const int y1B = min(y0B + 1, 31);

  for (int idx = threadIdx.x; idx < 132 * 64; idx += 256) {
    const int c = idx >> 6, x = idx & 63;
    float v;
    if (c < 4) {
      const float sx = x * s512;
      const int x0 = (int)sx;
      const float wx = sx - (float)x0;
      const int x1 = min(x0 + 1, 511);
      const float* im = inp + (size_t)(n * 4 + c) * 512 * 512;
      const float v00 = im[y0A * 512 + x0], v01 = im[y0A * 512 + x1];
      const float v10 = im[y1A * 512 + x0], v11 = im[y1A * 512 + x1];
      v = (v00 * (1.f - wx) + v01 * wx) * (1.f - wyA) +
          (v10 * (1.f - wx) + v11 * wx) * wyA;
    } else {
      const float* im = (c < 68) ? a32 + (size_t)(n * 64 + (c - 4)) * HW32
                                 : g32 + (size_t)(n * 64 + (c - 68)) * HW32;
      const float sx = x * s32;
      const int x0 = (int)sx;
      const float wx = sx - (float)x0;
      const int x1 = min(x0 + 1, 31);
      const float v00 = im[y0B * 32 + x0], v01 = im[y0B * 32 + x1];
      const float v10 = im[y1B * 32 + x0], v11 = im[y1B * 32 + x1];
      v = (v00 * (1.f - wx) + v01 * wx) * (1.f - wyB) +
          (v10 * (1.f - wx) + v11 * wx) * wyB;
    }
    feat[c * 64 + x] = v;
  }
  __syncthreads();

  const int x = threadIdx.x & 63;
  const int og = (threadIdx.x >> 6) * 32;

  float acc[32];
#pragma unroll
  for (int i = 0; i < 32; ++i) acc[i] = 0.f;

  for (int c0 = 0; c0 < 132; c0 += 4) {
    const float f0 = feat[(c0 + 0) * 64 + x];
    const float f1 = feat[(c0 + 1) * 64 + x];
    const float f2 = feat[(c0 + 2) * 64 + x];
    const float f3v = feat[(c0 + 3) * 64 + x];
#pragma unroll
    for (int i = 0; i < 32; ++i) {
      const float4 wv = *reinterpret_cast<const float4*>(&wlds[(og + i) * 132 + c0]);
      acc[i] = fmaf(wv.x, f0, acc[i]);
      acc[i] = fmaf(wv.y, f1, acc[i]);
      acc[i] = fmaf(wv.z, f2, acc[i]);
      acc[i] = fmaf(wv.w, f3v, acc[i]);
    }
  }

  float ss = 0.f;
#pragma unroll
  for (int i = 0; i < 32; ++i) ss = fmaf(acc[i], acc[i], ss);
  nrm[threadIdx.x >> 6][x] = ss;
  __syncthreads();
  const float tot = nrm[0][x] + nrm[1][x] + nrm[2][x] + nrm[3][x];
  const float inv = 1.f / (sqrtf(tot) + 1e-5f);

  const size_t base = ((size_t)n * HW64 + (size_t)y * 64 + x) * 128 + og;
#pragma unroll
  for (int i = 0; i < 32; ++i) fhi_g[base + i] = f2bf(acc[i] * inv);
}

// ---------------------------------------------------------------------------
// Kernel C: fused affinity+cam, plain bf16 MFMA, no w-LDS (intra-wave
// ds_bpermute C-frag -> B-frag reassembly).
// Block = 256 thr (4 waves; wave wq owns 64-wide q quarter). QB=256 q/block,
// p-range = 1024 per block (PSPLIT=4), tiles of PB=32.
// grid 512 = 16qt x 4ps x 8n, n in low bits (XCD L2 locality).
// Stage 1: acc[pf][qf] = S C-frags = mfma(F_p(LDS), F_q(VGPR)), K=128.
// Reassemble: relu -> cvt_pk bf16 pairs -> 8 bpermute + 4 cndmask per qf.
// Stage 2: nacc[rt][qf] += mfma(camA rows (global L2), W), K=32 per tile.
// part layout: [n][ps][22][4096]
// ---------------------------------------------------------------------------
__global__ __launch_bounds__(256) void k_fused(
    const u16* __restrict__ fhi_g, const u16* __restrict__ camA,
    float* __restrict__ part)
{
  __shared__ __align__(16) u16 fh[PB * FH_STR];   // 8.7 KB

  const int gx = blockIdx.x;
  const int n = gx & 7;
  const int rest = gx >> 3;
  const int qt = rest & 15;
  const int ps = rest >> 4;
  const int tid = threadIdx.x;
  const int lane = tid & 63;
  const int wq = tid >> 6;
  const int l15 = lane & 15;
  const int l4 = lane >> 4;
  const int qb = qt * 256;

  // q-side F fragments, resident in VGPRs (64 regs)
  bf16x8 Bq[4][4];
#pragma unroll
  for (int qf = 0; qf < 4; ++qf) {
    const size_t rowo = ((size_t)n * HW64 + qb + wq * 64 + qf * 16 + l15) * 128;
#pragma unroll
    for (int s = 0; s < 4; ++s)
      Bq[qf][s] = *(const bf16x8*)(fhi_g + rowo + s * 32 + l4 * 8);
  }

  f32x4 nacc[2][4];
#pragma unroll
  for (int rt = 0; rt < 2; ++rt)
#pragma unroll
    for (int qf = 0; qf < 4; ++qf) nacc[rt][qf] = {0.f, 0.f, 0.f, 0.f};

  const int srcA4 = (((lane & 16) << 1) + l15) << 2;  // (32*(l4&1)+l15)*4
  const int srcB4 = srcA4 + 64;
  const bool hi = (l4 >= 2);

  const int p_base = ps * (HW64 / PSPLIT);
  for (int t = 0; t < (HW64 / PSPLIT) / PB; ++t) {   // 32 tiles
    const int p0 = p_base + t * PB;
    __syncthreads();
    {   // stage F-tile: 32 rows x 128 ch bf16 (8 KB)
      const int p = tid >> 3;
      const int c = (tid & 7) * 16;
      const u16* src = fhi_g + ((size_t)n * HW64 + p0 + p) * 128 + c;
      *(bf16x8*)&fh[p * FH_STR + c] = *(const bf16x8*)src;
      *(bf16x8*)&fh[p * FH_STR + c + 8] = *(const bf16x8*)(src + 8);
    }
    __syncthreads();

    // ---- Stage 1: S C-frags, K=128
    f32x4 acc[2][4];
#pragma unroll
    for (int pf = 0; pf < 2; ++pf)
#pragma unroll
      for (int qf = 0; qf < 4; ++qf) acc[pf][qf] = {0.f, 0.f, 0.f, 0.f};

#pragma unroll
    for (int s = 0; s < 4; ++s) {
      bf16x8 Ah[2];
#pragma unroll
      for (int pf = 0; pf < 2; ++pf)
        Ah[pf] = *(const bf16x8*)&fh[(pf * 16 + l15) * FH_STR + s * 32 + l4 * 8];
#pragma unroll
      for (int pf = 0; pf < 2; ++pf)
#pragma unroll
        for (int qf = 0; qf < 4; ++qf)
          acc[pf][qf] = __builtin_amdgcn_mfma_f32_16x16x32_bf16(
              Ah[pf], Bq[qf][s], acc[pf][qf], 0, 0, 0);
    }

    // ---- relu + pack: P[pf][qf] = 2 dwords of bf16 pairs (k pf*16+l4*4+{0..3})
    u32 P[2][4][2];
#pragma unroll
    for (int pf = 0; pf < 2; ++pf)
#pragma unroll
      for (int qf = 0; qf < 4; ++qf) {
        const float v0 = fmaxf(acc[pf][qf][0], 0.f);
        const float v1 = fmaxf(acc[pf][qf][1], 0.f);
        const float v2 = fmaxf(acc[pf][qf][2], 0.f);
        const float v3 = fmaxf(acc[pf][qf][3], 0.f);
        u32 d0, d1;
        asm("v_cvt_pk_bf16_f32 %0, %1, %2" : "=v"(d0) : "v"(v0), "v"(v1));
        asm("v_cvt_pk_bf16_f32 %0, %1, %2" : "=v"(d1) : "v"(v2), "v"(v3));
        P[pf][qf][0] = d0;
        P[pf][qf][1] = d1;
      }

    // ---- cam A-frags for this tile (L2-resident bf16)
    bf16x8 Ac[2];
#pragma unroll
    for (int rt = 0; rt < 2; ++rt)
      Ac[rt] = *(const bf16x8*)(camA + ((size_t)n * 32 + rt * 16 + l15) * HW64 +
                                p0 + l4 * 8);

    // ---- Stage 2: B-frag assembly (intra-wave) + MFMA, K=32
#pragma unroll
    for (int qf = 0; qf < 4; ++qf) {
      const u32 w0a = (u32)__builtin_amdgcn_ds_bpermute(srcA4, (int)P[0][qf][0]);
      const u32 w0b = (u32)__builtin_amdgcn_ds_bpermute(srcA4, (int)P[1][qf][0]);
      const u32 w1a = (u32)__builtin_amdgcn_ds_bpermute(srcA4, (int)P[0][qf][1]);
      const u32 w1b = (u32)__builtin_amdgcn_ds_bpermute(srcA4, (int)P[1][qf][1]);
      const u32 w2a = (u32)__builtin_amdgcn_ds_bpermute(srcB4, (int)P[0][qf][0]);
      const u32 w2b = (u32)__builtin_amdgcn_ds_bpermute(srcB4, (int)P[1][qf][0]);
      const u32 w3a = (u32)__builtin_amdgcn_ds_bpermute(srcB4, (int)P[0][qf][1]);
      const u32 w3b = (u32)__builtin_amdgcn_ds_bpermute(srcB4, (int)P[1][qf][1]);
      union { u32 d[4]; bf16x8 v; } W;
      W.d[0] = hi ? w0b : w0a;
      W.d[1] = hi ? w1b : w1a;
      W.d[2] = hi ? w2b : w2a;
      W.d[3] = hi ? w3b : w3a;
      nacc[0][qf] = __builtin_amdgcn_mfma_f32_16x16x32_bf16(Ac[0], W.v, nacc[0][qf], 0, 0, 0);
      nacc[1][qf] = __builtin_amdgcn_mfma_f32_16x16x32_bf16(Ac[1], W.v, nacc[1][qf], 0, 0, 0);
    }
  }

  // ---- epilogue: rows = rt*16 + l4*4 + i (<22), cols = q
#pragma unroll
  for (int rt = 0; rt < 2; ++rt)
#pragma unroll
    for (int qf = 0; qf < 4; ++qf) {
      const int qg = qb + wq * 64 + qf * 16 + l15;
#pragma unroll
      for (int i = 0; i < 4; ++i) {
        const int row = rt * 16 + l4 * 4 + i;
        if (row < 22)
          part[(((size_t)n * PSPLIT + ps) * 22 + row) * HW64 + qg] = nacc[rt][qf][i];
      }
    }
}

// ---------------------------------------------------------------------------
// Kernel D: combine PSPLIT partials, divide.
// ---------------------------------------------------------------------------
__global__ __launch_bounds__(256) void k_final(
    const float* __restrict__ part, float* __restrict__ out, int total)
{
  const int idx = blockIdx.x * 256 + threadIdx.x;
  if (idx >= total) return;
  const int n = idx / (KCAM * HW64);
  const int r = idx - n * (KCAM * HW64);
  const int k = r >> 12;
  const int q = r & 4095;
  const float* base = part + (size_t)n * PSPLIT * 22 * HW64;
  float num = 0.f, den = 0.f;
#pragma unroll
  for (int p = 0; p < PSPLIT; ++p) {
    num += base[((size_t)p * 22 + k) * HW64 + q];
    den += base[((size_t)p * 22 + 21) * HW64 + q];
  }
  out[idx] = num / (den + 1e-5f);
}

// ---------------------------------------------------------------------------
extern "C" void kernel_launch(void* const* d_in, const int* in_sizes, int n_in,
                              void* d_out, int out_size, void* d_ws, size_t ws_size,
                              hipStream_t stream) {
  const float* aspp   = (const float*)d_in[0];
  const float* f3     = (const float*)d_in[1];
  const float* inp    = (const float*)d_in[2];
  const float* cam    = (const float*)d_in[3];
  const float* w_aspp = (const float*)d_in[4];
  const float* w_f3   = (const float*)d_in[5];
  const float* w_f9   = (const float*)d_in[6];
  float* out = (float*)d_out;

  float* ws   = (float*)d_ws;
  float* a32  = ws;                            // 524288 f32 (2 MB)
  float* g32  = a32 + 524288;                  // 524288 f32 (2 MB)
  float* part = g32 + 524288;                  // 8*4*22*4096 = 2883584 f32 (11.5 MB)
  u16*   fhi  = (u16*)(part + 2883584);        // 8*4096*128 u16 (8 MB)
  u16*   camA = fhi + 4194304;                 // 8*32*4096 u16 (2 MB)
  // total ~25.9 MB

  k_conv32<<<dim3(4, 4, 8), 256, 0, stream>>>(aspp, f3, w_aspp, w_f3, a32, g32);
  k_cam<<<4096, 256, 0, stream>>>(cam, camA);
  k_build_f<<<dim3(64, 8), 256, 0, stream>>>(inp, a32, g32, w_f9, fhi);
  k_fused<<<512, 256, 0, stream>>>(fhi, camA, part);
  k_final<<<2688, 256, 0, stream>>>(part, out, 8 * KCAM * HW64);
}

// Round 7
// 147.276 us; speedup vs baseline: 6.6202x; 1.0744x over previous
//
#include <hip/hip_runtime.h>
#include <math.h>

typedef unsigned short u16;
typedef unsigned int u32;
typedef __attribute__((ext_vector_type(8))) short bf16x8;
typedef __attribute__((ext_vector_type(4))) float f32x4;

#define HW32 1024
#define HW64 4096
#define KCAM 21
#define PB 32
#define PSPLIT 8
#define FH_STR 136   // u16 LDS row stride (128 + 8 pad): 272B -> conflict-free b128

static __device__ __forceinline__ u16 f2bf(float x) {
  u32 u = __float_as_uint(x);
  u32 r = (u + 0x7FFFu + ((u >> 16) & 1u)) >> 16;
  return (u16)r;
}

// ---------------------------------------------------------------------------
// Kernel A: 1x1 convs at 32x32 (f32). grid (4 ptiles, 2 which x 2 jhalf, 8 n).
// ---------------------------------------------------------------------------
__global__ __launch_bounds__(256) void k_conv32(
    const float* __restrict__ aspp, const float* __restrict__ f3,
    const float* __restrict__ w_aspp, const float* __restrict__ w_f3,
    float* __restrict__ a32, float* __restrict__ g32)
{
  const int pt = blockIdx.x, which = blockIdx.y >> 1, jh = blockIdx.y & 1,
            n = blockIdx.z;
  const float* x = (which == 0 ? aspp : f3) + (size_t)n * 128 * HW32;
  const float* w = (which == 0 ? w_aspp : w_f3) + jh * 32 * 128;
  float* out = (which == 0 ? a32 : g32) + (size_t)n * 64 * HW32 + (size_t)jh * 32 * HW32;

  __shared__ __align__(16) float wlds[32 * 128];
  for (int i = threadIdx.x; i < 32 * 128; i += 256) wlds[i] = w[i];
  __syncthreads();

  const int p = pt * 256 + threadIdx.x;
  float acc[32];
#pragma unroll
  for (int j = 0; j < 32; ++j) acc[j] = 0.f;

  for (int c0 = 0; c0 < 128; c0 += 8) {
    float xv[8];
#pragma unroll
    for (int cc = 0; cc < 8; ++cc) xv[cc] = x[(size_t)(c0 + cc) * HW32 + p];
#pragma unroll
    for (int j = 0; j < 32; ++j) {
      const float4 w0 = *reinterpret_cast<const float4*>(&wlds[j * 128 + c0]);
      const float4 w1 = *reinterpret_cast<const float4*>(&wlds[j * 128 + c0 + 4]);
      acc[j] = fmaf(w0.x, xv[0], acc[j]);
      acc[j] = fmaf(w0.y, xv[1], acc[j]);
      acc[j] = fmaf(w0.z, xv[2], acc[j]);
      acc[j] = fmaf(w0.w, xv[3], acc[j]);
      acc[j] = fmaf(w1.x, xv[4], acc[j]);
      acc[j] = fmaf(w1.y, xv[5], acc[j]);
      acc[j] = fmaf(w1.z, xv[6], acc[j]);
      acc[j] = fmaf(w1.w, xv[7], acc[j]);
    }
  }
  for (int j = 0; j < 32; ++j) out[(size_t)j * HW32 + p] = acc[j];
}

// ---------------------------------------------------------------------------
// Kernel B: build normalized f as bf16 (RN) [n][pos][128].
// 512 threads (8 waves): group g=tid>>6 handles 16 output channels.
// ---------------------------------------------------------------------------
__global__ __launch_bounds__(512) void k_build_f(
    const float* __restrict__ inp, const float* __restrict__ a32,
    const float* __restrict__ g32, const float* __restrict__ w_f9,
    u16* __restrict__ fhi_g)
{
  const int y = blockIdx.x, n = blockIdx.y;

  __shared__ __align__(16) float wlds[128 * 132];
  __shared__ float feat[132 * 64];
  __shared__ float nrm[8][64];

  for (int i = threadIdx.x; i < 128 * 132; i += 512) wlds[i] = w_f9[i];

  const float s512 = 511.f / 63.f, s32 = 31.f / 63.f;
  const float syA = y * s512;
  const int y0A = (int)syA;
  const float wyA = syA - (float)y0A;
  const int y1A = min(y0A + 1, 511);
  const float syB = y * s32;
  const int y0B = (int)syB;
  const float wyB = syB - (float)y0B;
  const int y1B = min(y0B + 1, 31);

  for (int idx = threadIdx.x; idx < 132 * 64; idx += 512) {
    const int c = idx >> 6, x = idx & 63;
    float v;
    if (c < 4) {
      const float sx = x * s512;
      const int x0 = (int)sx;
      const float wx = sx - (float)x0;
      const int x1 = min(x0 + 1, 511);
      const float* im = inp + (size_t)(n * 4 + c) * 512 * 512;
      const float v00 = im[y0A * 512 + x0], v01 = im[y0A * 512 + x1];
      const float v10 = im[y1A * 512 + x0], v11 = im[y1A * 512 + x1];
      v = (v00 * (1.f - wx) + v01 * wx) * (1.f - wyA) +
          (v10 * (1.f - wx) + v11 * wx) * wyA;
    } else {
      const float* im = (c < 68) ? a32 + (size_t)(n * 64 + (c - 4)) * HW32
                                 : g32 + (size_t)(n * 64 + (c - 68)) * HW32;
      const float sx = x * s32;
      const int x0 = (int)sx;
      const float wx = sx - (float)x0;
      const int x1 = min(x0 + 1, 31);
      const float v00 = im[y0B * 32 + x0], v01 = im[y0B * 32 + x1];
      const float v10 = im[y1B * 32 + x0], v11 = im[y1B * 32 + x1];
      v = (v00 * (1.f - wx) + v01 * wx) * (1.f - wyB) +
          (v10 * (1.f - wx) + v11 * wx) * wyB;
    }
    feat[c * 64 + x] = v;
  }
  __syncthreads();

  const int x = threadIdx.x & 63;
  const int g = threadIdx.x >> 6;
  const int og = g * 16;

  float acc[16];
#pragma unroll
  for (int i = 0; i < 16; ++i) acc[i] = 0.f;

  for (int c0 = 0; c0 < 132; c0 += 4) {
    const float f0 = feat[(c0 + 0) * 64 + x];
    const float f1 = feat[(c0 + 1) * 64 + x];
    const float f2 = feat[(c0 + 2) * 64 + x];
    const float f3v = feat[(c0 + 3) * 64 + x];
#pragma unroll
    for (int i = 0; i < 16; ++i) {
      const float4 wv = *reinterpret_cast<const float4*>(&wlds[(og + i) * 132 + c0]);
      acc[i] = fmaf(wv.x, f0, acc[i]);
      acc[i] = fmaf(wv.y, f1, acc[i]);
      acc[i] = fmaf(wv.z, f2, acc[i]);
      acc[i] = fmaf(wv.w, f3v, acc[i]);
    }
  }

  float ss = 0.f;
#pragma unroll
  for (int i = 0; i < 16; ++i) ss = fmaf(acc[i], acc[i], ss);
  nrm[g][x] = ss;
  __syncthreads();
  float tot = 0.f;
#pragma unroll
  for (int gg = 0; gg < 8; ++gg) tot += nrm[gg][x];
  const float inv = 1.f / (sqrtf(tot) + 1e-5f);

  const size_t base = ((size_t)n * HW64 + (size_t)y * 64 + x) * 128 + og;
#pragma unroll
  for (int i = 0; i < 16; ++i) fhi_g[base + i] = f2bf(acc[i] * inv);
}

// ---------------------------------------------------------------------------
// Kernel C: fused affinity+cam, plain bf16 MFMA, no w-LDS (intra-wave
// ds_bpermute C-frag -> B-frag reassembly). cam converted in-register.
// Block = 256 thr (4 waves; wave wq owns 64-wide q quarter). 256 q/block,
// p-range = 512 per block (PSPLIT=8), tiles of PB=32.
// grid 1024 = 8ps x 16qt x 8n, n in low bits (XCD L2 locality).
// part layout: [n][ps][22][4096]
// ---------------------------------------------------------------------------
__global__ __launch_bounds__(256) void k_fused(
    const u16* __restrict__ fhi_g, const float* __restrict__ cam,
    float* __restrict__ part)
{
  __shared__ __align__(16) u16 fh[PB * FH_STR];   // 8.7 KB

  const int gx = blockIdx.x;
  const int n = gx & 7;
  const int rest = gx >> 3;
  const int qt = rest & 15;
  const int ps = rest >> 4;
  const int tid = threadIdx.x;
  const int lane = tid & 63;
  const int wq = tid >> 6;
  const int l15 = lane & 15;
  const int l4 = lane >> 4;
  const int qb = qt * 256;

  // q-side F fragments, resident in VGPRs (64 regs)
  bf16x8 Bq[4][4];
#pragma unroll
  for (int qf = 0; qf < 4; ++qf) {
    const size_t rowo = ((size_t)n * HW64 + qb + wq * 64 + qf * 16 + l15) * 128;
#pragma unroll
    for (int s = 0; s < 4; ++s)
      Bq[qf][s] = *(const bf16x8*)(fhi_g + rowo + s * 32 + l4 * 8);
  }

  f32x4 nacc[2][4];
#pragma unroll
  for (int rt = 0; rt < 2; ++rt)
#pragma unroll
    for (int qf = 0; qf < 4; ++qf) nacc[rt][qf] = {0.f, 0.f, 0.f, 0.f};

  const int srcA4 = (((lane & 16) << 1) + l15) << 2;  // (32*(l4&1)+l15)*4
  const int srcB4 = srcA4 + 64;
  const bool hi = (l4 >= 2);

  // cam row indices for the in-register A-frag conversion
  const int r1 = 16 + l15;                       // rt=1 row
  const int r1c = (r1 < KCAM) ? r1 : (KCAM - 1); // clamped for safe address
  const float fill1 = (r1 == KCAM) ? 1.f : 0.f;  // row 21 = ones, >21 = zeros

  const int p_base = ps * (HW64 / PSPLIT);
  for (int t = 0; t < (HW64 / PSPLIT) / PB; ++t) {   // 16 tiles
    const int p0 = p_base + t * PB;
    __syncthreads();
    {   // stage F-tile: 32 rows x 128 ch bf16 (8 KB)
      const int p = tid >> 3;
      const int c = (tid & 7) * 16;
      const u16* src = fhi_g + ((size_t)n * HW64 + p0 + p) * 128 + c;
      *(bf16x8*)&fh[p * FH_STR + c] = *(const bf16x8*)src;
      *(bf16x8*)&fh[p * FH_STR + c + 8] = *(const bf16x8*)(src + 8);
    }
    __syncthreads();

    // ---- Stage 1: S C-frags, K=128
    f32x4 acc[2][4];
#pragma unroll
    for (int pf = 0; pf < 2; ++pf)
#pragma unroll
      for (int qf = 0; qf < 4; ++qf) acc[pf][qf] = {0.f, 0.f, 0.f, 0.f};

#pragma unroll
    for (int s = 0; s < 4; ++s) {
      bf16x8 Ah[2];
#pragma unroll
      for (int pf = 0; pf < 2; ++pf)
        Ah[pf] = *(const bf16x8*)&fh[(pf * 16 + l15) * FH_STR + s * 32 + l4 * 8];
#pragma unroll
      for (int pf = 0; pf < 2; ++pf)
#pragma unroll
        for (int qf = 0; qf < 4; ++qf)
          acc[pf][qf] = __builtin_amdgcn_mfma_f32_16x16x32_bf16(
              Ah[pf], Bq[qf][s], acc[pf][qf], 0, 0, 0);
    }

    // ---- relu + pack: P[pf][qf] = 2 dwords of bf16 pairs
    u32 P[2][4][2];
#pragma unroll
    for (int pf = 0; pf < 2; ++pf)
#pragma unroll
      for (int qf = 0; qf < 4; ++qf) {
        const float v0 = fmaxf(acc[pf][qf][0], 0.f);
        const float v1 = fmaxf(acc[pf][qf][1], 0.f);
        const float v2 = fmaxf(acc[pf][qf][2], 0.f);
        const float v3 = fmaxf(acc[pf][qf][3], 0.f);
        u32 d0, d1;
        asm("v_cvt_pk_bf16_f32 %0, %1, %2" : "=v"(d0) : "v"(v0), "v"(v1));
        asm("v_cvt_pk_bf16_f32 %0, %1, %2" : "=v"(d1) : "v"(v2), "v"(v3));
        P[pf][qf][0] = d0;
        P[pf][qf][1] = d1;
      }

    // ---- cam A-frags for this tile: load f32, convert in-register
    bf16x8 Ac[2];
    {
      union { u32 d[4]; bf16x8 v; } A0, A1;
      // rt = 0: rows l15 = 0..15, all < 21
      const float* c0p = cam + (size_t)(n * KCAM + l15) * HW64 + p0 + l4 * 8;
      const float4 u0 = *reinterpret_cast<const float4*>(c0p);
      const float4 u1 = *reinterpret_cast<const float4*>(c0p + 4);
      asm("v_cvt_pk_bf16_f32 %0, %1, %2" : "=v"(A0.d[0]) : "v"(u0.x), "v"(u0.y));
      asm("v_cvt_pk_bf16_f32 %0, %1, %2" : "=v"(A0.d[1]) : "v"(u0.z), "v"(u0.w));
      asm("v_cvt_pk_bf16_f32 %0, %1, %2" : "=v"(A0.d[2]) : "v"(u1.x), "v"(u1.y));
      asm("v_cvt_pk_bf16_f32 %0, %1, %2" : "=v"(A0.d[3]) : "v"(u1.z), "v"(u1.w));
      Ac[0] = A0.v;
      // rt = 1: rows 16+l15 (21 -> ones, >21 -> zeros)
      const float* c1p = cam + (size_t)(n * KCAM + r1c) * HW64 + p0 + l4 * 8;
      float4 w0 = *reinterpret_cast<const float4*>(c1p);
      float4 w1 = *reinterpret_cast<const float4*>(c1p + 4);
      if (r1 >= KCAM) {
        w0.x = w0.y = w0.z = w0.w = fill1;
        w1.x = w1.y = w1.z = w1.w = fill1;
      }
      asm("v_cvt_pk_bf16_f32 %0, %1, %2" : "=v"(A1.d[0]) : "v"(w0.x), "v"(w0.y));
      asm("v_cvt_pk_bf16_f32 %0, %1, %2" : "=v"(A1.d[1]) : "v"(w0.z), "v"(w0.w));
      asm("v_cvt_pk_bf16_f32 %0, %1, %2" : "=v"(A1.d[2]) : "v"(w1.x), "v"(w1.y));
      asm("v_cvt_pk_bf16_f32 %0, %1, %2" : "=v"(A1.d[3]) : "v"(w1.z), "v"(w1.w));
      Ac[1] = A1.v;
    }

    // ---- Stage 2: B-frag assembly (intra-wave) + MFMA, K=32
#pragma unroll
    for (int qf = 0; qf < 4; ++qf) {
      const u32 w0a = (u32)__builtin_amdgcn_ds_bpermute(srcA4, (int)P[0][qf][0]);
      const u32 w0b = (u32)__builtin_amdgcn_ds_bpermute(srcA4, (int)P[1][qf][0]);
      const u32 w1a = (u32)__builtin_amdgcn_ds_bpermute(srcA4, (int)P[0][qf][1]);
      const u32 w1b = (u32)__builtin_amdgcn_ds_bpermute(srcA4, (int)P[1][qf][1]);
      const u32 w2a = (u32)__builtin_amdgcn_ds_bpermute(srcB4, (int)P[0][qf][0]);
      const u32 w2b = (u32)__builtin_amdgcn_ds_bpermute(srcB4, (int)P[1][qf][0]);
      const u32 w3a = (u32)__builtin_amdgcn_ds_bpermute(srcB4, (int)P[0][qf][1]);
      const u32 w3b = (u32)__builtin_amdgcn_ds_bpermute(srcB4, (int)P[1][qf][1]);
      union { u32 d[4]; bf16x8 v; } W;
      W.d[0] = hi ? w0b : w0a;
      W.d[1] = hi ? w1b : w1a;
      W.d[2] = hi ? w2b : w2a;
      W.d[3] = hi ? w3b : w3a;
      nacc[0][qf] = __builtin_amdgcn_mfma_f32_16x16x32_bf16(Ac[0], W.v, nacc[0][qf], 0, 0, 0);
      nacc[1][qf] = __builtin_amdgcn_mfma_f32_16x16x32_bf16(Ac[1], W.v, nacc[1][qf], 0, 0, 0);
    }
  }

  // ---- epilogue: rows = rt*16 + l4*4 + i (<22), cols = q
#pragma unroll
  for (int rt = 0; rt < 2; ++rt)
#pragma unroll
    for (int qf = 0; qf < 4; ++qf) {
      const int qg = qb + wq * 64 + qf * 16 + l15;
#pragma unroll
      for (int i = 0; i < 4; ++i) {
        const int row = rt * 16 + l4 * 4 + i;
        if (row < 22)
          part[(((size_t)n * PSPLIT + ps) * 22 + row) * HW64 + qg] = nacc[rt][qf][i];
      }
    }
}

// ---------------------------------------------------------------------------
// Kernel D: combine PSPLIT partials, divide.
// ---------------------------------------------------------------------------
__global__ __launch_bounds__(256) void k_final(
    const float* __restrict__ part, float* __restrict__ out, int total)
{
  const int idx = blockIdx.x * 256 + threadIdx.x;
  if (idx >= total) return;
  const int n = idx / (KCAM * HW64);
  const int r = idx - n * (KCAM * HW64);
  const int k = r >> 12;
  const int q = r & 4095;
  const float* base = part + (size_t)n * PSPLIT * 22 * HW64;
  float num = 0.f, den = 0.f;
#pragma unroll
  for (int p = 0; p < PSPLIT; ++p) {
    num += base[((size_t)p * 22 + k) * HW64 + q];
    den += base[((size_t)p * 22 + 21) * HW64 + q];
  }
  out[idx] = num / (den + 1e-5f);
}

// ---------------------------------------------------------------------------
extern "C" void kernel_launch(void* const* d_in, const int* in_sizes, int n_in,
                              void* d_out, int out_size, void* d_ws, size_t ws_size,
                              hipStream_t stream) {
  const float* aspp   = (const float*)d_in[0];
  const float* f3     = (const float*)d_in[1];
  const float* inp    = (const float*)d_in[2];
  const float* cam    = (const float*)d_in[3];
  const float* w_aspp = (const float*)d_in[4];
  const float* w_f3   = (const float*)d_in[5];
  const float* w_f9   = (const float*)d_in[6];
  float* out = (float*)d_out;

  // Workspace layout (31.1 MB):
  //   [0,    8MB)  fhi  (u16, 8*4096*128)          written by k_build_f
  //   [8MB, 31.1MB) part (f32, 8*8*22*4096)        written by k_fused
  //   a32/g32 (2MB each) ALIAS part's first 4MB: they are produced by
  //   k_conv32, consumed by k_build_f, and dead before k_fused writes part
  //   (all launches are stream-ordered).
  u16*   fhi  = (u16*)d_ws;
  float* part = (float*)(fhi + 4194304);
  float* a32  = part;
  float* g32  = a32 + 524288;

  k_conv32<<<dim3(4, 4, 8), 256, 0, stream>>>(aspp, f3, w_aspp, w_f3, a32, g32);
  k_build_f<<<dim3(64, 8), 512, 0, stream>>>(inp, a32, g32, w_f9, fhi);
  k_fused<<<1024, 256, 0, stream>>>(fhi, cam, part);
  k_final<<<2688, 256, 0, stream>>>(part, out, 8 * KCAM * HW64);
}